// Round 15
// baseline (219.926 us; speedup 1.0000x reference)
//
#include <hip/hip_runtime.h>

#define B_ 4
#define N_ 4096
#define H_ 256
#define BN_ (B_*N_)
#define NSPLIT 4
#define L2E 1.44269504088896340736f

typedef _Float16 f16;
typedef f16 f16x4 __attribute__((ext_vector_type(4)));
typedef f16 f16x8 __attribute__((ext_vector_type(8)));
typedef float f32x4 __attribute__((ext_vector_type(4)));
typedef float f32x16 __attribute__((ext_vector_type(16)));

static __device__ __forceinline__ f32x4 mfma16(f16x8 a, f16x8 b, f32x4 c){
  return __builtin_amdgcn_mfma_f32_16x16x32_f16(a, b, c, 0, 0, 0);
}
static __device__ __forceinline__ f32x16 mfma32(f16x8 a, f16x8 b, f32x16 c){
  return __builtin_amdgcn_mfma_f32_32x32x16_f16(a, b, c, 0, 0, 0);
}

// async global->LDS, 16B per lane; LDS dest is wave-uniform base + lane*16
static __device__ __forceinline__ void gload16(const void* g, void* l){
  __builtin_amdgcn_global_load_lds(
    (const __attribute__((address_space(1))) unsigned int*)g,
    (__attribute__((address_space(3))) unsigned int*)l, 16, 0, 0);
}

static __device__ __forceinline__ f16x8 cvt8(const float* __restrict__ p){
  float4 f0 = *(const float4*)p, f1 = *(const float4*)(p + 4);
  f16x8 v;
  v[0]=(f16)f0.x; v[1]=(f16)f0.y; v[2]=(f16)f0.z; v[3]=(f16)f0.w;
  v[4]=(f16)f1.x; v[5]=(f16)f1.y; v[6]=(f16)f1.z; v[7]=(f16)f1.w;
  return v;
}

// Convert 3 f32 weight matrices [256][256] into frag-ordered f16 layout.
__global__ __launch_bounds__(256) void cvt_w_frag(
    const float* __restrict__ W0, const float* __restrict__ W1,
    const float* __restrict__ W2, f16* __restrict__ Wf){
  int u = blockIdx.x * 256 + threadIdx.x;        // [0, 3*8192)
  int m = u >> 13, u13 = u & 8191;
  const float* W = (m == 0) ? W0 : ((m == 1) ? W1 : W2);
  int ol = u13 & 31, t = u13 >> 5;
  int hi = t & 1, ks = (t >> 1) & 15, ot = t >> 5;
  int o = ot*32 + ol;
  *(f16x8*)(Wf + (size_t)u * 8) = cvt8(W + o*256 + ks*16 + hi*8);
}

// Fused QKV projection (R12 structure — inline f32->f16 conversion in staging).
__global__ __launch_bounds__(512, 2) void proj_qkv(
    const float* __restrict__ X, const f16* __restrict__ Wf,
    const float* __restrict__ bq, const float* __restrict__ bk,
    const float* __restrict__ bv,
    f16* __restrict__ Yq, f16* __restrict__ Yk, f16* __restrict__ Yvt){
  __shared__ f16 Xl[64*256];    // 32KB
  const int tid = threadIdx.x, l = tid & 63, w = tid >> 6;
  const int ol = l & 31, hi = l >> 5;
  const int m0 = blockIdx.x * 64;

  #pragma unroll
  for (int i = 0; i < 4; ++i){           // 2048 16B chunks / 512 threads
    int c = i*512 + tid;
    int r = c >> 5, x = c & 31;
    f16x8 v = cvt8(X + (size_t)(m0 + r)*H_ + ((x ^ (r & 7)) << 3));
    *(f16x8*)(Xl + (size_t)c*8) = v;
  }
  __syncthreads();

  f32x16 aq[2], ak[2], av[2];
  #pragma unroll
  for (int ms = 0; ms < 2; ++ms)
    #pragma unroll
    for (int e = 0; e < 16; ++e){ aq[ms][e]=0.f; ak[ms][e]=0.f; av[ms][e]=0.f; }

  const char* Xb = (const char*)Xl;
  #pragma unroll
  for (int ks = 0; ks < 16; ++ks){
    int cw = ks*2 + hi;
    f16x8 a0 = *(const f16x8*)(Xb + ((     ol)*32 + (cw ^ (ol & 7))) * 16);
    f16x8 a1 = *(const f16x8*)(Xb + ((32 + ol)*32 + (cw ^ (ol & 7))) * 16);
    size_t wu = ((size_t)((w*16 + ks)*2 + hi))*256 + ol*8;
    f16x8 wqf = *(const f16x8*)(Wf + wu);
    f16x8 wkf = *(const f16x8*)(Wf + 65536 + wu);
    f16x8 wvf = *(const f16x8*)(Wf + 131072 + wu);
    aq[0] = mfma32(a0, wqf, aq[0]);  aq[1] = mfma32(a1, wqf, aq[1]);
    ak[0] = mfma32(a0, wkf, ak[0]);  ak[1] = mfma32(a1, wkf, ak[1]);
    av[0] = mfma32(a0, wvf, av[0]);  av[1] = mfma32(a1, wvf, av[1]);
  }

  const int o = w*32 + ol;
  const float Bq = bq[o], Bk = bk[o], Bv = bv[o];
  const int bb = m0 >> 12;
  const int nn0 = m0 & (N_-1);
  #pragma unroll
  for (int ms = 0; ms < 2; ++ms){
    #pragma unroll
    for (int rg = 0; rg < 4; ++rg){
      int rbase = m0 + ms*32 + 8*rg + 4*hi;
      f16x4 pk;
      #pragma unroll
      for (int j = 0; j < 4; ++j){
        float vq = (ms ? aq[1][4*rg+j] : aq[0][4*rg+j]) + Bq;
        float vk = (ms ? ak[1][4*rg+j] : ak[0][4*rg+j]) + Bk;
        float vv = (ms ? av[1][4*rg+j] : av[0][4*rg+j]) + Bv;
        Yq[(size_t)(rbase + j)*H_ + o] = (f16)vq;
        Yk[(size_t)(rbase + j)*H_ + o] = (f16)vk;
        pk[j] = (f16)vv;
      }
      *(f16x4*)(Yvt + ((size_t)(bb*H_ + o))*N_ + nn0 + ms*32 + 8*rg + 4*hi) = pk;
    }
  }
}

// Flash attention R14: 16x16 fragments (R2-verified maps) for register relief.
// 8 waves x 16 q rows (QBLK=128), KVB=32, kv-split x4 (grid 512 = 2 blocks/CU).
// Per wave: qf 32 + oacc 64 regs -> launch_bounds(512,4) caps at 128 ->
// 4 waves/SIMD. LDS 74KB: K dbuf (row-swizzled), V dbuf [f][ch] chunk-minor
// (gload_lds linear dest, 64B-coalesced source, bank-uniform PV reads),
// per-wave P relay (within-wave write->read, no barrier; R2 precedent).
// One __syncthreads per tile. Writes normalized f16 partial + log-sum.
__global__ __launch_bounds__(512, 4) void flash_kernel(
    const f16* __restrict__ Q, const f16* __restrict__ K,
    const f16* __restrict__ Vt, f16* __restrict__ Opn, float* __restrict__ mll){
  __shared__ __align__(16) char lds[75776];
  f16* Kl = (f16*)lds;                    // [2][32 rows][256] 32KB
  f16* Vl = (f16*)(lds + 32768);          // [2][256 f][4 ch][8] 32KB
  f16* Pl = (f16*)(lds + 65536);          // [8][16*40] 10KB

  const int tid = threadIdx.x, l = tid & 63, w = tid >> 6;
  const int lr = l & 15, g = l >> 4;      // lane row / k-group
  const int qblk = blockIdx.x >> 2, ks = blockIdx.x & 3;
  const int b = qblk >> 5, qt = qblk & 31;
  const int q0 = qt * 128;
  const int kvbase = ks * 1024;
  const f16* Kg = K  + (size_t)b * N_ * H_;
  const f16* Vg = Vt + (size_t)b * H_ * N_;

  // hoist Q A-frags: wave's 16 q rows; lane holds row lr, k-chunk kk*32+g*8
  f16x8 qf[8];
  {
    const f16* qp = Q + ((size_t)b*N_ + q0 + w*16 + lr) * H_ + g*8;
    #pragma unroll
    for (int kk = 0; kk < 8; ++kk) qf[kk] = *(const f16x8*)(qp + kk*32);
  }

  f32x4 oacc[16];
  #pragma unroll
  for (int ft = 0; ft < 16; ++ft) oacc[ft] = {0.f,0.f,0.f,0.f};
  float m_run[4], l_run[4];
  #pragma unroll
  for (int r = 0; r < 4; ++r){ m_run[r] = -3.0e38f; l_run[r] = 0.f; }

  auto stage = [&](int buf, int t){
    const int kv0 = kvbase + t * 32;
    #pragma unroll
    for (int i = 0; i < 2; ++i){          // K: 1024 chunks (32 rows x 512B)
      int c = i*512 + tid;
      int r = c >> 5, x = c & 31;
      gload16(Kg + (size_t)(kv0 + r)*H_ + ((x ^ (r & 7)) << 3),
              Kl + buf*8192 + (i*512 + (tid & ~63)) * 8);
    }
    #pragma unroll
    for (int i = 0; i < 2; ++i){          // V chunk-minor: chunk c = f*4 + ch
      int c = i*512 + tid;
      int f = c >> 2, ch = c & 3;
      gload16(Vg + (size_t)f*N_ + kv0 + ch*8,
              Vl + buf*8192 + (i*512 + (tid & ~63)) * 8);
    }
  };

  stage(0, 0);
  __syncthreads();

  f16* Pw = Pl + w*640;
  for (int t = 0; t < 32; ++t){
    const int cur = t & 1;
    if (t + 1 < 32) stage(cur ^ 1, t + 1);   // prefetch next tile

    // ---- S = Q K^T : 16q x 32kv (C: row q=g*4+r, col kv=ct*16+lr)
    f32x4 s[2];
    s[0] = {0.f,0.f,0.f,0.f}; s[1] = {0.f,0.f,0.f,0.f};
    const char* Kb = (const char*)(Kl + cur*8192);
    __builtin_amdgcn_s_setprio(1);
    #pragma unroll
    for (int kk = 0; kk < 8; ++kk){
      const int cw = kk*4 + g;
      #pragma unroll
      for (int ct = 0; ct < 2; ++ct){
        const int n = ct*16 + lr;
        f16x8 kf = *(const f16x8*)(Kb + n*512 + ((cw ^ (n & 7)) << 4));
        s[ct] = mfma16(qf[kk], kf, s[ct]);
      }
    }
    __builtin_amdgcn_s_setprio(0);

    // ---- online softmax (rows g*4+r; cols over 16 lanes x 2 ct)
    float mx[4];
    #pragma unroll
    for (int r = 0; r < 4; ++r) mx[r] = fmaxf(s[0][r], s[1][r]);
    #pragma unroll
    for (int d = 1; d < 16; d <<= 1)
      #pragma unroll
      for (int r = 0; r < 4; ++r) mx[r] = fmaxf(mx[r], __shfl_xor(mx[r], d));
    float al[4];
    #pragma unroll
    for (int r = 0; r < 4; ++r){
      float mn = fmaxf(m_run[r], mx[r]);
      al[r] = __builtin_amdgcn_exp2f((m_run[r] - mn) * L2E);
      m_run[r] = mn;
    }
    float ps[4] = {0.f,0.f,0.f,0.f};
    #pragma unroll
    for (int ct = 0; ct < 2; ++ct)
      #pragma unroll
      for (int r = 0; r < 4; ++r){
        float p = __builtin_amdgcn_exp2f((s[ct][r] - m_run[r]) * L2E);
        s[ct][r] = p; ps[r] += p;
      }
    #pragma unroll
    for (int d = 1; d < 16; d <<= 1)
      #pragma unroll
      for (int r = 0; r < 4; ++r) ps[r] += __shfl_xor(ps[r], d);
    #pragma unroll
    for (int r = 0; r < 4; ++r) l_run[r] = l_run[r]*al[r] + ps[r];
    #pragma unroll
    for (int ft = 0; ft < 16; ++ft)
      #pragma unroll
      for (int r = 0; r < 4; ++r) oacc[ft][r] *= al[r];

    // ---- P relay: within-wave LDS write -> read as A-frag (no barrier)
    #pragma unroll
    for (int ct = 0; ct < 2; ++ct)
      #pragma unroll
      for (int r = 0; r < 4; ++r)
        Pw[(g*4 + r)*40 + ct*16 + lr] = (f16)s[ct][r];
    f16x8 af = *(const f16x8*)(Pw + lr*40 + g*8);

    // ---- O += P V : B-frag lane holds f=ft*16+lr, kv-chunk g -> chunk f*4+g
    const f16* Vb = Vl + cur*8192 + (size_t)(lr*4 + g)*8;
    __builtin_amdgcn_s_setprio(1);
    #pragma unroll
    for (int ft = 0; ft < 16; ++ft){
      f16x8 vf = *(const f16x8*)(Vb + (size_t)ft*512);  // +ft*16 f -> +ft*64 chunks
      oacc[ft] = mfma16(af, vf, oacc[ft]);
    }
    __builtin_amdgcn_s_setprio(0);
    __syncthreads();   // drains vmcnt(0): next-tile stage complete
  }

  // ---- epilogue: normalized f16 partial + log-sum (no in-block merge)
  float inv[4];
  #pragma unroll
  for (int r = 0; r < 4; ++r) inv[r] = 1.0f / l_run[r];
  const size_t rowbase = (size_t)b*N_ + q0 + w*16 + g*4;
  #pragma unroll
  for (int ft = 0; ft < 16; ++ft)
    #pragma unroll
    for (int r = 0; r < 4; ++r)
      Opn[((size_t)ks*BN_ + rowbase + r)*H_ + ft*16 + lr] =
        (f16)(oacc[ft][r] * inv[r]);
  if (lr == 0){
    #pragma unroll
    for (int r = 0; r < 4; ++r)
      mll[(size_t)ks*BN_ + rowbase + r] = m_run[r]*L2E + __log2f(l_run[r]);
  }
}

// Combine the 4 kv-split partials: out = sum_s w_s*O_s / sum_s w_s
__global__ __launch_bounds__(256) void merge_kernel(
    const f16* __restrict__ Opn, const float* __restrict__ mll,
    float* __restrict__ out){
  int i = blockIdx.x*256 + threadIdx.x;   // one 4-feature chunk
  int row = i >> 6, c = i & 63;
  float gv[NSPLIT];
  float gm = -3.0e38f;
  #pragma unroll
  for (int s = 0; s < NSPLIT; ++s){
    gv[s] = mll[(size_t)s*BN_ + row];
    gm = fmaxf(gm, gv[s]);
  }
  float acc0=0.f, acc1=0.f, acc2=0.f, acc3=0.f, wsum=0.f;
  #pragma unroll
  for (int s = 0; s < NSPLIT; ++s){
    float wv = __builtin_amdgcn_exp2f(gv[s] - gm);
    f16x4 a = *(const f16x4*)(Opn + ((size_t)s*BN_ + row)*H_ + c*4);
    acc0 += wv*(float)a[0]; acc1 += wv*(float)a[1];
    acc2 += wv*(float)a[2]; acc3 += wv*(float)a[3];
    wsum += wv;
  }
  float inv = 1.0f / wsum;
  float4 o; o.x = acc0*inv; o.y = acc1*inv; o.z = acc2*inv; o.w = acc3*inv;
  *(float4*)(out + (size_t)row*H_ + c*4) = o;
}

extern "C" void kernel_launch(void* const* d_in, const int* in_sizes, int n_in,
                              void* d_out, int out_size, void* d_ws, size_t ws_size,
                              hipStream_t stream) {
  const float* x  = (const float*)d_in[0];
  const float* Wq = (const float*)d_in[1];
  const float* bq = (const float*)d_in[2];
  const float* Wk = (const float*)d_in[3];
  const float* bk = (const float*)d_in[4];
  const float* Wv = (const float*)d_in[5];
  const float* bv = (const float*)d_in[6];
  float* out = (float*)d_out;

  // workspace layout (~57 MB): wf overlays opn (dead before flash writes opn)
  char* ws = (char*)d_ws;
  const size_t SZ = (size_t)BN_ * H_ * 2;              // 8 MB
  f16*   qb  = (f16*)(ws);
  f16*   kb  = (f16*)(ws + SZ);
  f16*   vt  = (f16*)(ws + 2*SZ);                      // [B][H][N]
  f16*   opn = (f16*)(ws + 3*SZ);                      // [4][BN][H] f16 (32MB)
  float* mll = (float*)(ws + 3*SZ + (size_t)NSPLIT*SZ);// [4][BN] f32 (256KB)
  f16*   wf  = (f16*)(ws + 3*SZ);                      // fragged W (384KB, pre-flash)

  cvt_w_frag<<<96, 256, 0, stream>>>(Wq, Wk, Wv, wf);
  proj_qkv<<<BN_/64, 512, 0, stream>>>(x, wf, bq, bk, bv, qb, kb, vt);
  flash_kernel<<<(BN_/128)*NSPLIT, 512, 0, stream>>>(qb, kb, vt, opn, mll);
  merge_kernel<<<BN_*64/256, 256, 0, stream>>>(opn, mll, out);
}

// Round 16
// 121.201 us; speedup vs baseline: 1.8146x; 1.8146x over previous
//
#include <hip/hip_runtime.h>

#define B_ 4
#define N_ 4096
#define H_ 256
#define BN_ (B_*N_)
#define L2E 1.44269504088896340736f

typedef _Float16 f16;
typedef __fp16 fp16x2 __attribute__((ext_vector_type(2)));
typedef f16 f16x4 __attribute__((ext_vector_type(4)));
typedef f16 f16x8 __attribute__((ext_vector_type(8)));
typedef float f32x4 __attribute__((ext_vector_type(4)));
typedef float f32x16 __attribute__((ext_vector_type(16)));
typedef unsigned u32x2 __attribute__((ext_vector_type(2)));

static __device__ __forceinline__ f32x16 mfma32(f16x8 a, f16x8 b, f32x16 c){
  return __builtin_amdgcn_mfma_f32_32x32x16_f16(a, b, c, 0, 0, 0);
}
static __device__ __forceinline__ unsigned pkrtz(float a, float b){
  fp16x2 h = __builtin_amdgcn_cvt_pkrtz(a, b);
  return __builtin_bit_cast(unsigned, h);
}
static __device__ __forceinline__ u32x2 pls(unsigned a, unsigned b){
#if __has_builtin(__builtin_amdgcn_permlane32_swap)
  return __builtin_amdgcn_permlane32_swap(a, b, false, false);
#else
  asm volatile("v_permlane32_swap_b32 %0, %1" : "+v"(a), "+v"(b));
  u32x2 r; r[0] = a; r[1] = b; return r;
#endif
}
static __device__ __forceinline__ u32x2 plsf(float a, float b){
  return pls(__builtin_bit_cast(unsigned, a), __builtin_bit_cast(unsigned, b));
}
static __device__ __forceinline__ float asf(unsigned u){
  return __builtin_bit_cast(float, u);
}

// async global->LDS, 16B per lane; LDS dest is wave-uniform base + lane*16
static __device__ __forceinline__ void gload16(const void* g, void* l){
  __builtin_amdgcn_global_load_lds(
    (const __attribute__((address_space(1))) unsigned int*)g,
    (__attribute__((address_space(3))) unsigned int*)l, 16, 0, 0);
}

static __device__ __forceinline__ f16x8 cvt8(const float* __restrict__ p){
  float4 f0 = *(const float4*)p, f1 = *(const float4*)(p + 4);
  f16x8 v;
  v[0]=(f16)f0.x; v[1]=(f16)f0.y; v[2]=(f16)f0.z; v[3]=(f16)f0.w;
  v[4]=(f16)f1.x; v[5]=(f16)f1.y; v[6]=(f16)f1.z; v[7]=(f16)f1.w;
  return v;
}

// Convert 3 f32 weight matrices [256][256] into frag-ordered f16 layout.
__global__ __launch_bounds__(256) void cvt_w_frag(
    const float* __restrict__ W0, const float* __restrict__ W1,
    const float* __restrict__ W2, f16* __restrict__ Wf){
  int u = blockIdx.x * 256 + threadIdx.x;        // [0, 3*8192)
  int m = u >> 13, u13 = u & 8191;
  const float* W = (m == 0) ? W0 : ((m == 1) ? W1 : W2);
  int ol = u13 & 31, t = u13 >> 5;
  int hi = t & 1, ks = (t >> 1) & 15, ot = t >> 5;
  int o = ot*32 + ol;
  *(f16x8*)(Wf + (size_t)u * 8) = cvt8(W + o*256 + ks*16 + hi*8);
}

// Fused QKV projection; reads x as f32 and converts during LDS staging
// (reg-stage + ds_write to the SAME offsets global_load_lds produced).
__global__ __launch_bounds__(512, 2) void proj_qkv(
    const float* __restrict__ X, const f16* __restrict__ Wf,
    const float* __restrict__ bq, const float* __restrict__ bk,
    const float* __restrict__ bv,
    f16* __restrict__ Yq, f16* __restrict__ Yk, f16* __restrict__ Yvt){
  __shared__ f16 Xl[64*256];    // 32KB
  const int tid = threadIdx.x, l = tid & 63, w = tid >> 6;
  const int ol = l & 31, hi = l >> 5;
  const int m0 = blockIdx.x * 64;

  #pragma unroll
  for (int i = 0; i < 4; ++i){           // 2048 16B chunks / 512 threads
    int c = i*512 + tid;
    int r = c >> 5, x = c & 31;
    f16x8 v = cvt8(X + (size_t)(m0 + r)*H_ + ((x ^ (r & 7)) << 3));
    *(f16x8*)(Xl + (size_t)c*8) = v;     // chunk c -> byte c*16 (same as gload16)
  }
  __syncthreads();

  f32x16 aq[2], ak[2], av[2];
  #pragma unroll
  for (int ms = 0; ms < 2; ++ms)
    #pragma unroll
    for (int e = 0; e < 16; ++e){ aq[ms][e]=0.f; ak[ms][e]=0.f; av[ms][e]=0.f; }

  const char* Xb = (const char*)Xl;
  #pragma unroll
  for (int ks = 0; ks < 16; ++ks){
    int cw = ks*2 + hi;
    f16x8 a0 = *(const f16x8*)(Xb + ((     ol)*32 + (cw ^ (ol & 7))) * 16);
    f16x8 a1 = *(const f16x8*)(Xb + ((32 + ol)*32 + (cw ^ (ol & 7))) * 16);
    size_t wu = ((size_t)((w*16 + ks)*2 + hi))*256 + ol*8;
    f16x8 wqf = *(const f16x8*)(Wf + wu);
    f16x8 wkf = *(const f16x8*)(Wf + 65536 + wu);
    f16x8 wvf = *(const f16x8*)(Wf + 131072 + wu);
    aq[0] = mfma32(a0, wqf, aq[0]);  aq[1] = mfma32(a1, wqf, aq[1]);
    ak[0] = mfma32(a0, wkf, ak[0]);  ak[1] = mfma32(a1, wkf, ak[1]);
    av[0] = mfma32(a0, wvf, av[0]);  av[1] = mfma32(a1, wvf, av[1]);
  }

  const int o = w*32 + ol;
  const float Bq = bq[o], Bk = bk[o], Bv = bv[o];
  const int bb = m0 >> 12;
  const int nn0 = m0 & (N_-1);
  #pragma unroll
  for (int ms = 0; ms < 2; ++ms){
    #pragma unroll
    for (int rg = 0; rg < 4; ++rg){
      int rbase = m0 + ms*32 + 8*rg + 4*hi;
      f16x4 pk;
      #pragma unroll
      for (int j = 0; j < 4; ++j){
        float vq = (ms ? aq[1][4*rg+j] : aq[0][4*rg+j]) + Bq;
        float vk = (ms ? ak[1][4*rg+j] : ak[0][4*rg+j]) + Bk;
        float vv = (ms ? av[1][4*rg+j] : av[0][4*rg+j]) + Bv;
        Yq[(size_t)(rbase + j)*H_ + o] = (f16)vq;
        Yk[(size_t)(rbase + j)*H_ + o] = (f16)vk;
        pk[j] = (f16)vv;
      }
      *(f16x4*)(Yvt + ((size_t)(bb*H_ + o))*N_ + nn0 + ms*32 + 8*rg + 4*hi) = pk;
    }
  }
}

// Flash attention (R8 structure — best measured: 102us, MfmaUtil 28%).
// 32x32 MFMA, swapped operands, QBLK=128, kv-split x2; 8 waves = 4 q-strips
// x 2 kv-halves; in-block kv-half merge; permlane cross-half exchanges.
// Structural ceiling (R7-R15 measured): per-wave state qf64+oacc128 ~= 256
// unified regs -> 2 waves/SIMD; 4-strip LDS duplication -> 256KB reads/tile;
// all occupancy/schedule alternatives measured worse.
__global__ __launch_bounds__(512, 2) void flash_kernel(
    const f16* __restrict__ Q, const f16* __restrict__ K,
    const f16* __restrict__ Vt, f16* __restrict__ Opn, float* __restrict__ mll){
  __shared__ __align__(16) char lds[132*1024];
  f16* Kl0 = (f16*)lds;                   // [2][64*256]  64KB
  f16* Vl0 = (f16*)(lds + 65536);         // [2][256*64]  64KB
  float* mlb = (float*)(lds + 131072);    // 256 floats

  const int tid = threadIdx.x, l = tid & 63, w = tid >> 6;
  const int q32 = l & 31, hi = l >> 5;
  const int strip = w & 3, kvh = w >> 2;
  const int qblk = blockIdx.x >> 1, kb = blockIdx.x & 1;
  const int b = qblk >> 5, qt = qblk & 31;
  const int q0 = qt * 128;
  const int kvbase = kb * 2048;
  const f16* Kg = K  + (size_t)b * N_ * H_;
  const f16* Vg = Vt + (size_t)b * H_ * N_;

  f16x8 qf[16];
  {
    const f16* qp = Q + ((size_t)b*N_ + q0 + strip*32 + q32) * H_ + hi*8;
    #pragma unroll
    for (int ks = 0; ks < 16; ++ks) qf[ks] = *(const f16x8*)(qp + ks*16);
  }

  f32x16 oacc[8];
  #pragma unroll
  for (int ft = 0; ft < 8; ++ft)
    #pragma unroll
    for (int e = 0; e < 16; ++e) oacc[ft][e] = 0.f;
  float m_run = -3.0e38f, l_run = 0.f;

  auto stage = [&](int buf, int t){
    const int kv0 = kvbase + t * 64;
    #pragma unroll
    for (int i = 0; i < 4; ++i){
      int c = i*512 + tid;
      int r = c >> 5, x = c & 31;
      gload16(Kg + (size_t)(kv0 + r)*H_ + ((x ^ (r & 7)) << 3),
              Kl0 + buf*16384 + (i*512 + (tid & ~63)) * 8);
    }
    #pragma unroll
    for (int i = 0; i < 4; ++i){
      int c = i*512 + tid;
      int f = c >> 3, x = c & 7;
      gload16(Vg + (size_t)f*N_ + kv0 + ((x ^ (f & 7)) << 3),
              Vl0 + buf*16384 + (i*512 + (tid & ~63)) * 8);
    }
  };

  stage(0, 0);
  __syncthreads();

  const int krow = kvh*32 + q32;
  for (int t = 0; t < 32; ++t){
    const int cur = t & 1;
    if (t + 1 < 32) stage(cur ^ 1, t + 1);

    f32x16 s;
    #pragma unroll
    for (int e = 0; e < 16; ++e) s[e] = 0.f;
    const char* Kb = (const char*)(Kl0 + cur*16384);
    __builtin_amdgcn_s_setprio(1);
    #pragma unroll
    for (int ks = 0; ks < 16; ++ks){
      int cw = ks*2 + hi;
      f16x8 ka = *(const f16x8*)(Kb + krow*512 + ((cw ^ (krow & 7)) << 4));
      s = mfma32(ka, qf[ks], s);
    }
    __builtin_amdgcn_s_setprio(0);

    float m8[8];
    #pragma unroll
    for (int e = 0; e < 8; ++e) m8[e] = fmaxf(s[e], s[e+8]);
    #pragma unroll
    for (int e = 0; e < 4; ++e) m8[e] = fmaxf(m8[e], m8[e+4]);
    float mloc = fmaxf(fmaxf(m8[0], m8[2]), fmaxf(m8[1], m8[3]));
    u32x2 mr = plsf(mloc, mloc);
    float mx = fmaxf(asf(mr[0]), asf(mr[1]));
    if (!__all(mx - m_run <= 8.0f)){
      float mn = fmaxf(m_run, mx);
      float al = __builtin_amdgcn_exp2f((m_run - mn) * L2E);
      m_run = mn; l_run *= al;
      #pragma unroll
      for (int ft = 0; ft < 8; ++ft)
        #pragma unroll
        for (int e = 0; e < 16; ++e) oacc[ft][e] *= al;
    }
    #pragma unroll
    for (int e = 0; e < 16; ++e)
      s[e] = __builtin_amdgcn_exp2f((s[e] - m_run) * L2E);
    float p8[8];
    #pragma unroll
    for (int e = 0; e < 8; ++e) p8[e] = s[e] + s[e+8];
    #pragma unroll
    for (int e = 0; e < 4; ++e) p8[e] = p8[e] + p8[e+4];
    float ps = (p8[0] + p8[2]) + (p8[1] + p8[3]);
    u32x2 pr = plsf(ps, ps);
    l_run += asf(pr[0]) + asf(pr[1]);

    unsigned xw[4], yw[4];
    #pragma unroll
    for (int o = 0; o < 4; ++o){
      xw[o] = pkrtz(s[4*o],   s[4*o+1]);
      yw[o] = pkrtz(s[4*o+2], s[4*o+3]);
    }

    const char* Vb = (const char*)(Vl0 + cur*16384);
    #pragma unroll
    for (int ks2 = 0; ks2 < 2; ++ks2){
      u32x2 r0 = pls(xw[2*ks2], xw[2*ks2+1]);
      u32x2 r1 = pls(yw[2*ks2], yw[2*ks2+1]);
      union { unsigned u[4]; f16x8 v; } pa;
      pa.u[0] = r0[0];
      pa.u[1] = r1[0];
      pa.u[2] = r0[1];
      pa.u[3] = r1[1];
      __builtin_amdgcn_s_setprio(1);
      #pragma unroll
      for (int ft = 0; ft < 8; ++ft){
        int f  = ft*32 + q32;
        int cw = kvh*4 + ks2*2 + hi;
        f16x8 va = *(const f16x8*)(Vb + f*128 + ((cw ^ (f & 7)) << 4));
        oacc[ft] = mfma32(va, pa.v, oacc[ft]);
      }
      __builtin_amdgcn_s_setprio(0);
    }
    __syncthreads();
  }

  __syncthreads();
  float* scr = (float*)lds;
  if (kvh == 1){
    #pragma unroll
    for (int ft = 0; ft < 8; ++ft)
      #pragma unroll
      for (int rg = 0; rg < 4; ++rg){
        int c = 8*ft + 2*rg + hi;
        f32x4 v = { oacc[ft][4*rg], oacc[ft][4*rg+1],
                    oacc[ft][4*rg+2], oacc[ft][4*rg+3] };
        *(f32x4*)(scr + strip*8192 + q32*256 + (c ^ (q32 & 7))*4) = v;
      }
    if (hi == 0){ mlb[strip*32 + q32] = m_run; mlb[128 + strip*32 + q32] = l_run; }
  }
  __syncthreads();
  if (kvh == 0){
    float mB = mlb[strip*32 + q32], lB = mlb[128 + strip*32 + q32];
    float mM = fmaxf(m_run, mB);
    float e0 = __builtin_amdgcn_exp2f((m_run - mM) * L2E);
    float e1 = __builtin_amdgcn_exp2f((mB    - mM) * L2E);
    float lM = e0*l_run + e1*lB;
    float inv = 1.0f / lM;
    size_t row = (size_t)b*N_ + q0 + strip*32 + q32;
    f16* od = Opn + ((size_t)kb*BN_ + row) * H_;
    #pragma unroll
    for (int ft = 0; ft < 8; ++ft)
      #pragma unroll
      for (int rg = 0; rg < 4; ++rg){
        int c = 8*ft + 2*rg + hi;
        f32x4 vB = *(const f32x4*)(scr + strip*8192 + q32*256 + (c ^ (q32 & 7))*4);
        f16x4 hv;
        #pragma unroll
        for (int j = 0; j < 4; ++j)
          hv[j] = (f16)((e0*oacc[ft][4*rg+j] + e1*vB[j]) * inv);
        *(f16x4*)(od + 32*ft + 8*rg + 4*hi) = hv;
      }
    if (hi == 0) mll[(size_t)kb*BN_ + row] = mM*L2E + __log2f(lM);
  }
}

// Combine the two kv-split partials: out = (w0*O0n + w1*O1n)/(w0+w1)
__global__ __launch_bounds__(256) void merge_kernel(
    const f16* __restrict__ Opn, const float* __restrict__ mll,
    float* __restrict__ out){
  int i = blockIdx.x*256 + threadIdx.x;
  int row = i >> 6, c = i & 63;
  float g0 = mll[row], g1 = mll[BN_ + row];
  float gm = fmaxf(g0, g1);
  float w0 = __builtin_amdgcn_exp2f(g0 - gm);
  float w1 = __builtin_amdgcn_exp2f(g1 - gm);
  float inv = 1.0f / (w0 + w1);
  f16x4 a  = *(const f16x4*)(Opn + (size_t)row*H_ + c*4);
  f16x4 bq = *(const f16x4*)(Opn + ((size_t)BN_ + row)*H_ + c*4);
  float4 o;
  o.x = (w0*(float)a[0] + w1*(float)bq[0]) * inv;
  o.y = (w0*(float)a[1] + w1*(float)bq[1]) * inv;
  o.z = (w0*(float)a[2] + w1*(float)bq[2]) * inv;
  o.w = (w0*(float)a[3] + w1*(float)bq[3]) * inv;
  *(float4*)(out + (size_t)row*H_ + c*4) = o;
}

extern "C" void kernel_launch(void* const* d_in, const int* in_sizes, int n_in,
                              void* d_out, int out_size, void* d_ws, size_t ws_size,
                              hipStream_t stream) {
  const float* x  = (const float*)d_in[0];
  const float* Wq = (const float*)d_in[1];
  const float* bq = (const float*)d_in[2];
  const float* Wk = (const float*)d_in[3];
  const float* bk = (const float*)d_in[4];
  const float* Wv = (const float*)d_in[5];
  const float* bv = (const float*)d_in[6];
  float* out = (float*)d_out;

  // workspace layout (~41 MB)
  char* ws = (char*)d_ws;
  const size_t SZ = (size_t)BN_ * H_ * 2;              // 8 MB
  f16*   qb  = (f16*)(ws);
  f16*   kb  = (f16*)(ws + SZ);
  f16*   vt  = (f16*)(ws + 2*SZ);                      // [B][H][N]
  f16*   opn = (f16*)(ws + 3*SZ);                      // [2][BN][H] f16 (16MB)
  float* mll = (float*)(ws + 5*SZ);                    // [2][BN] f32 (128KB)
  f16*   wf  = (f16*)(ws + 5*SZ + 131072);             // fragged W (384KB)

  cvt_w_frag<<<96, 256, 0, stream>>>(Wq, Wk, Wv, wf);
  proj_qkv<<<BN_/64, 512, 0, stream>>>(x, wf, bq, bk, bv, qb, kb, vt);
  flash_kernel<<<(BN_/128)*2, 512, 0, stream>>>(qb, kb, vt, opn, mll);
  merge_kernel<<<BN_*64/256, 256, 0, stream>>>(opn, mll, out);
}